// Round 5
// baseline (487.172 us; speedup 1.0000x reference)
//
#include <hip/hip_runtime.h>
#include <math.h>

#define BB 1024
#define TT 50
#define FF 48
#define EXTN 60
#define NFREQ 31

typedef _Float16 h8 __attribute__((ext_vector_type(8)));
typedef _Float16 h4 __attribute__((ext_vector_type(4)));
typedef float f4 __attribute__((ext_vector_type(4)));

__device__ __forceinline__ float fast_tanh(float x) {
    float e = __expf(2.0f * x);
    return 1.0f - 2.0f * __builtin_amdgcn_rcpf(e + 1.0f);
}

// ---------------- fused prep: weight transpose/convert + padded atts + DCT tables ----------------
// blocks [0,256): gcb transpose; [256,384): Wt1p (512x64); [384,416): Wt7p (16x512);
// [416,488): att_pad 6 x (48x64); [488,492): dctm+dtail.
__global__ void prep_kernel(const float* __restrict__ gcb_w, _Float16* __restrict__ Wtb,
                            const float* __restrict__ gc1_w, _Float16* __restrict__ Wt1p,
                            const float* __restrict__ gc7_w, _Float16* __restrict__ Wt7p,
                            const float* __restrict__ gc1_att, const float* __restrict__ gcb_att,
                            const float* __restrict__ gc7_att, _Float16* __restrict__ att_pad,
                            float* __restrict__ dctm, float* __restrict__ dtail) {
    __shared__ _Float16 t[64][72];
    int blk = blockIdx.x, tid = threadIdx.x;
    if (blk < 256) {
        int z = blk >> 6, rem = blk & 63;
        int n0 = (rem & 7) * 64, k0 = (rem >> 3) * 64;
        const float* Ws = gcb_w + (size_t)z * 262144;
        _Float16* Wd = Wtb + (size_t)z * 262144;
        for (int i = tid; i < 4096; i += 256) {
            int r = i >> 6, c = i & 63;
            t[r][c] = (_Float16)Ws[(size_t)(k0 + r) * 512 + n0 + c];
        }
        __syncthreads();
        for (int i = tid; i < 4096; i += 256) {
            int r = i >> 6, c = i & 63;
            Wd[(size_t)(n0 + r) * 512 + k0 + c] = t[c][r];
        }
    } else if (blk < 384) {
        int idx = (blk - 256) * 256 + tid;
        int n = idx >> 6, k = idx & 63;
        Wt1p[idx] = (k < 10) ? (_Float16)gc1_w[k * 512 + n] : (_Float16)0.0f;
    } else if (blk < 416) {
        int idx = (blk - 384) * 256 + tid;
        if (idx < 8192) {
            int n = idx >> 9, k = idx & 511;
            Wt7p[idx] = (n < 10) ? (_Float16)gc7_w[k * 10 + n] : (_Float16)0.0f;
        }
    } else if (blk < 488) {
        int idx = (blk - 416) * 256 + tid;
        if (idx < 18432) {
            int l = idx / 3072, r = (idx % 3072) / 64, m = idx & 63;
            float v = 0.f;
            if (m < 48) {
                v = (l == 0) ? gc1_att[r * 48 + m]
                  : (l <= 4) ? gcb_att[(l - 1) * 2304 + r * 48 + m]
                             : gc7_att[r * 48 + m];
            }
            att_pad[idx] = (_Float16)v;
        }
    } else {
        int idx = (blk - 488) * 256 + tid;
        if (idx < 900) {
            int d = idx / 30, k = idx % 30;
            double w = (d == 0) ? sqrt(1.0 / 30.0) : sqrt(2.0 / 30.0);
            dctm[idx] = (float)(w * cos(M_PI * (k + 0.5) * d / 30.0));
        } else if (idx < 910) {
            int d = idx - 900;
            double w = (d == 0) ? sqrt(1.0 / 30.0) : sqrt(2.0 / 30.0);
            double s = 0.0;
            for (int k = 10; k < 30; ++k) s += w * cos(M_PI * (k + 0.5) * d / 30.0);
            dtail[d] = (float)s;
        }
    }
}

// ---------------- dct_in[b,f,d] = sum_k dctm[d,k]*gcn_in[k,f]; f16 copy padded to 64 ----------------
__global__ void dct_in_kernel(const float* __restrict__ seq, const float* __restrict__ dctm,
                              const float* __restrict__ dtail, float* __restrict__ dct_in,
                              _Float16* __restrict__ dct_in_h, int Bc) {
    int idx = blockIdx.x * blockDim.x + threadIdx.x;
    if (idx >= Bc * 3072) return;
    int b = idx / 3072, r = idx % 3072;
    int f = r >> 6, d = r & 63;
    float acc = 0.f;
    if (d < 10) {
        const float* s = seq + (size_t)b * TT * FF;
        acc = dtail[d] * s[49 * FF + f];
        #pragma unroll
        for (int k = 0; k < 10; ++k) acc += dctm[d * 30 + k] * s[(40 + k) * FF + f];
        dct_in[(size_t)b * 480 + f * 10 + d] = acc;
    }
    dct_in_h[idx] = (_Float16)acc;
}

// ---------------- one GCN layer on LDS-resident state ----------------
// State S: 48 rows x 1024 B (512 f16 channels), 16B granules XOR-swizzled by (row&7).
// Main: D1 = S @ W  (A = state rows m, B = Wt rows n, direct-from-global frags).
// Mix:  new = tanh(att @ D1 + bias) [+resid]; operand-swapped MFMA so output is
// channel-contiguous h4 -> single ds_write_b64 per tile into S.
// MODE 0: plain tanh. MODE 1: tanh + save old state to sv. MODE 2: tanh + add sv.
template<int KSTEPS, int MODE>
__device__ __forceinline__ void gcn_layer(char* S, char* T,
        const _Float16* __restrict__ Wt, const _Float16* __restrict__ attp,
        const float* __restrict__ bias, h4* sv,
        int lane, int wv, int l16, int quad) {
    // att B-frags (rows i, k=m zero-padded to 64), hoisted, from global (L2-hot)
    h8 ab[3][2];
    #pragma unroll
    for (int it = 0; it < 3; ++it)
        #pragma unroll
        for (int ks = 0; ks < 2; ++ks)
            ab[it][ks] = *(const h8*)(attp + (it * 16 + l16) * 64 + ks * 32 + quad * 8);

    f4 acc[3][8];
    #pragma unroll
    for (int mt = 0; mt < 3; ++mt)
        #pragma unroll
        for (int nt = 0; nt < 8; ++nt) acc[mt][nt] = (f4)0.0f;

    __syncthreads();   // state ready for reading
    const int xm = l16 & 7;
    #pragma unroll 2
    for (int ks = 0; ks < KSTEPS; ++ks) {
        h8 a[3], bfr[8];
        #pragma unroll
        for (int nt = 0; nt < 8; ++nt)
            bfr[nt] = *(const h8*)(Wt + (size_t)(wv * 128 + nt * 16 + l16) * (KSTEPS * 32) + ks * 32 + quad * 8);
        #pragma unroll
        for (int mt = 0; mt < 3; ++mt)
            a[mt] = *(h8*)(S + (mt * 16 + l16) * 1024 + (((ks * 4 + quad) ^ xm) << 4));
        #pragma unroll
        for (int mt = 0; mt < 3; ++mt)
            #pragma unroll
            for (int nt = 0; nt < 8; ++nt)
                acc[mt][nt] = __builtin_amdgcn_mfma_f32_16x16x32_f16(a[mt], bfr[nt], acc[mt][nt], 0, 0, 0);
    }
    __syncthreads();   // all waves done reading state; epilogue may overwrite

    // zero transit pads (m=48..63 + stagger), wave-local
    if (lane < 48) {
        int row = lane / 3, s = lane % 3;
        *(h8*)(T + row * 144 + 96 + s * 16) = (h8)(_Float16)0.0f;
    }

    #pragma unroll
    for (int nt = 0; nt < 8; ++nt) {
        // transit: C^T tile (16 n-rows x 48 m) as f16, h4-contiguous writes
        #pragma unroll
        for (int mt = 0; mt < 3; ++mt) {
            h4 hv;
            #pragma unroll
            for (int j = 0; j < 4; ++j) hv[j] = (_Float16)acc[mt][nt][j];
            *(h4*)(T + l16 * 144 + (mt * 16 + quad * 4) * 2) = hv;
        }
        asm volatile("s_waitcnt lgkmcnt(0)" ::: "memory");
        h8 tf0 = *(h8*)(T + l16 * 144 + quad * 16);
        h8 tf1 = *(h8*)(T + l16 * 144 + 64 + quad * 16);
        f4 acc2[3];
        #pragma unroll
        for (int it = 0; it < 3; ++it) {
            acc2[it] = __builtin_amdgcn_mfma_f32_16x16x32_f16(tf0, ab[it][0], (f4)0.0f, 0, 0, 0);
            acc2[it] = __builtin_amdgcn_mfma_f32_16x16x32_f16(tf1, ab[it][1], acc2[it], 0, 0, 0);
        }
        const int c0 = wv * 128 + nt * 16 + quad * 4;
        const f4 bv = *(const f4*)(bias + c0);
        #pragma unroll
        for (int it = 0; it < 3; ++it) {
            int f = it * 16 + l16;
            char* sp = S + f * 1024 + (((c0 >> 3) ^ (f & 7)) << 4) + ((c0 & 7) << 1);
            if (MODE == 1) sv[nt * 3 + it] = *(h4*)sp;
            h4 o;
            #pragma unroll
            for (int j = 0; j < 4; ++j) {
                float v = fast_tanh(acc2[it][j] + bv[j]);
                if (MODE == 2) v += (float)sv[nt * 3 + it][j];
                o[j] = (_Float16)v;
            }
            *(h4*)sp = o;
        }
    }
}

// ---------------- fused GCN: L1..L6 + recon, state in LDS, one WG per batch ----------------
__launch_bounds__(256, 2)
__global__ void gcn_fused_kernel(const _Float16* __restrict__ dct_in_h,
                                 const float* __restrict__ dct_in,
                                 const _Float16* __restrict__ Wt1p,
                                 const _Float16* __restrict__ Wtb,
                                 const _Float16* __restrict__ Wt7p,
                                 const _Float16* __restrict__ attp,
                                 const float* __restrict__ gc1_b,
                                 const float* __restrict__ gcb_b,
                                 const float* __restrict__ gc7_b,
                                 const float* __restrict__ dctm,
                                 float* __restrict__ fusedb) {
    __shared__ __align__(16) char smem[61440];
    char* S = smem;                 // 48 x 1024 B state (swizzled)
    char* R = smem + 49152;         // 12,288 B: per-wave transit / L6 partials / G
    const int tid = threadIdx.x, lane = tid & 63, wv = tid >> 6;
    const int l16 = lane & 15, quad = lane >> 4;
    const int b = blockIdx.x;
    char* T = R + wv * 2304;

    // stage dct_in (48 x 64 f16) into swizzled state
    for (int v = tid; v < 384; v += 256) {
        int m = v >> 3, g = v & 7;
        *(h8*)(S + m * 1024 + ((g ^ (m & 7)) << 4)) =
            *(const h8*)(dct_in_h + (size_t)b * 3072 + m * 64 + g * 8);
    }

    h4 sv[24];
    gcn_layer<2, 0>(S, T, Wt1p,          attp,         gc1_b,        sv, lane, wv, l16, quad);
    gcn_layer<16, 1>(S, T, Wtb,          attp + 3072,  gcb_b,        sv, lane, wv, l16, quad);
    gcn_layer<16, 2>(S, T, Wtb + 262144, attp + 6144,  gcb_b + 512,  sv, lane, wv, l16, quad);
    gcn_layer<16, 1>(S, T, Wtb + 524288, attp + 9216,  gcb_b + 1024, sv, lane, wv, l16, quad);
    gcn_layer<16, 2>(S, T, Wtb + 786432, attp + 12288, gcb_b + 1536, sv, lane, wv, l16, quad);

    // ---- L6 (gc7, N=16 padded, fp32) + recon ----
    __syncthreads();
    {
        f4 acc[3];
        #pragma unroll
        for (int mt = 0; mt < 3; ++mt) acc[mt] = (f4)0.0f;
        #pragma unroll
        for (int ks = 0; ks < 4; ++ks) {
            int kh = wv * 128 + ks * 32;
            h8 bfr = *(const h8*)(Wt7p + (size_t)l16 * 512 + kh + quad * 8);
            #pragma unroll
            for (int mt = 0; mt < 3; ++mt) {
                h8 a = *(h8*)(S + (mt * 16 + l16) * 1024 + ((((kh >> 3) + quad) ^ (l16 & 7)) << 4));
                acc[mt] = __builtin_amdgcn_mfma_f32_16x16x32_f16(a, bfr, acc[mt], 0, 0, 0);
            }
        }
        #pragma unroll
        for (int mt = 0; mt < 3; ++mt)
            *(f4*)(R + wv * 3072 + l16 * 192 + (mt * 16 + quad * 4) * 4) = acc[mt];
    }
    __syncthreads();
    if (wv == 0) {
        // sum 4 wave-partials -> f16 transit T6 (at R base, rows n=16 x m pad 64)
        h4 tw[3]; int ns[3], ms[3];
        #pragma unroll
        for (int q = 0; q < 3; ++q) {
            int idx = lane * 3 + q;
            int n = idx / 12, m0 = (idx % 12) * 4;
            f4 s = *(f4*)(R + n * 192 + m0 * 4);
            s += *(f4*)(R + 3072 + n * 192 + m0 * 4);
            s += *(f4*)(R + 6144 + n * 192 + m0 * 4);
            s += *(f4*)(R + 9216 + n * 192 + m0 * 4);
            h4 h;
            #pragma unroll
            for (int j = 0; j < 4; ++j) h[j] = (_Float16)s[j];
            tw[q] = h; ns[q] = n; ms[q] = m0;
        }
        asm volatile("s_waitcnt lgkmcnt(0)" ::: "memory");
        #pragma unroll
        for (int q = 0; q < 3; ++q) *(h4*)(R + ns[q] * 144 + ms[q] * 2) = tw[q];
        if (lane < 48) {
            int row = lane / 3, s2 = lane % 3;
            *(h8*)(R + row * 144 + 96 + s2 * 16) = (h8)(_Float16)0.0f;
        }
        asm volatile("s_waitcnt lgkmcnt(0)" ::: "memory");
        h8 tf0 = *(h8*)(R + l16 * 144 + quad * 16);
        h8 tf1 = *(h8*)(R + l16 * 144 + 64 + quad * 16);
        const _Float16* a7 = attp + 15360;
        f4 acc2[3];
        #pragma unroll
        for (int it = 0; it < 3; ++it) {
            h8 ab0 = *(const h8*)(a7 + (it * 16 + l16) * 64 + quad * 8);
            h8 ab1 = *(const h8*)(a7 + (it * 16 + l16) * 64 + 32 + quad * 8);
            acc2[it] = __builtin_amdgcn_mfma_f32_16x16x32_f16(tf0, ab0, (f4)0.0f, 0, 0, 0);
            acc2[it] = __builtin_amdgcn_mfma_f32_16x16x32_f16(tf1, ab1, acc2[it], 0, 0, 0);
        }
        char* G = R + 4096;   // 48 x 16 f32, pitch 64
        #pragma unroll
        for (int it = 0; it < 3; ++it) {
            int f = it * 16 + l16;
            #pragma unroll
            for (int j = 0; j < 4; ++j) {
                int c = quad * 4 + j;
                if (c < 10) {
                    float v = acc2[it][j] + gc7_b[c] + dct_in[(size_t)b * 480 + f * 10 + c];
                    *(float*)(G + f * 64 + c * 4) = v;
                }
            }
        }
    }
    __syncthreads();
    {
        char* G = R + 4096;
        for (int v = tid; v < 1440; v += 256) {
            int f = v / 30, t = v % 30;
            float s = 0.f;
            #pragma unroll
            for (int d = 0; d < 10; ++d) s += dctm[d * 30 + t] * *(float*)(G + f * 64 + d * 4);
            fusedb[(size_t)b * 1920 + f * 40 + t] = s;
        }
    }
}

// ---------------- FFC branch (direct DFT; only first 10 irfft samples needed) --------
__launch_bounds__(256)
__global__ void ffc_kernel(const float* __restrict__ seq, const float* __restrict__ wl,
                           const float* __restrict__ wg, float* __restrict__ fused) {
    int b = blockIdx.x, tid = threadIdx.x;
    __shared__ float ext[EXTN][FF];
    __shared__ float Xre[FF][32];
    __shared__ float Xim[FF][32];
    __shared__ float Yo[6][16][32];
    __shared__ float c60[60], s60[60];
    __shared__ float wls[9], wgs[36];
    const float* s = seq + (size_t)b * TT * FF;
    for (int idx = tid; idx < EXTN * FF; idx += 256) {
        int t = idx / FF, f = idx % FF;
        int ts = t < TT ? t : TT - 1;
        ext[t][f] = s[ts * FF + f];
    }
    if (tid < 60) { c60[tid] = cospif(tid / 30.0f); s60[tid] = sinpif(tid / 30.0f); }
    if (tid >= 64 && tid < 73) wls[tid - 64] = wl[tid - 64];
    if (tid >= 128 && tid < 164) wgs[tid - 128] = wg[tid - 128];
    __syncthreads();
    for (int idx = tid; idx < FF * NFREQ; idx += 256) {
        int f = idx % FF, k = idx / FF;
        float re = 0.f, im = 0.f;
        int kt = 0;
        for (int t = 0; t < EXTN; ++t) {
            float v = ext[t][f];
            re += v * c60[kt];
            im -= v * s60[kt];
            kt += k; kt = (kt >= 60) ? kt - 60 : kt;
        }
        Xre[f][k] = re; Xim[f][k] = im;
    }
    __syncthreads();
    for (int idx = tid; idx < 6 * 16 * NFREQ; idx += 256) {
        int k = idx % NFREQ; int g = (idx / NFREQ) % 16; int o = idx / (NFREQ * 16);
        float v = wgs[o * 6 + 0] * Xre[g][k]      + wgs[o * 6 + 1] * Xre[16 + g][k]
                + wgs[o * 6 + 2] * Xre[32 + g][k] + wgs[o * 6 + 3] * Xim[g][k]
                + wgs[o * 6 + 4] * Xim[16 + g][k] + wgs[o * 6 + 5] * Xim[32 + g][k];
        Yo[o][g][k] = fmaxf(v, 0.f);
    }
    __syncthreads();
    for (int idx = tid; idx < 480; idx += 256) {
        int t = idx % 10; int g = (idx / 10) % 16; int c = idx / 160;
        float acc = Yo[c][g][0] + Yo[c][g][30] * ((t & 1) ? -1.f : 1.f);
        float s2 = 0.f;
        int kt = t;
        for (int k = 1; k < 30; ++k) {
            s2 += Yo[c][g][k] * c60[kt] - Yo[c + 3][g][k] * s60[kt];
            kt += t; kt = (kt >= 60) ? kt - 60 : kt;
        }
        acc = (acc + 2.f * s2) * (1.0f / 60.0f);
        float loc = wls[c * 3 + 0] * ext[t][g] + wls[c * 3 + 1] * ext[t][16 + g]
                  + wls[c * 3 + 2] * ext[t][32 + g];
        int f = c * 16 + g;
        fused[(size_t)b * 1920 + f * 40 + 30 + t] = acc + loc;
    }
}

// ---------------- MLP head (only first 10 of 40 output rows needed) ----------------
__launch_bounds__(256)
__global__ void mlp_kernel(const float* __restrict__ fused, const float* __restrict__ w1,
                           const float* __restrict__ w2, float* __restrict__ out) {
    int b = blockIdx.x, tid = threadIdx.x;
    __shared__ float fs[48][40];
    __shared__ float hs[48][257];
    for (int idx = tid; idx < 1920; idx += 256) fs[idx / 40][idx % 40] = fused[(size_t)b * 1920 + idx];
    __syncthreads();
    for (int idx = tid; idx < 48 * 256; idx += 256) {
        int o = idx & 255, f = idx >> 8;
        const float* wr = w1 + o * 40;
        float s = 0.f;
        #pragma unroll
        for (int t = 0; t < 40; ++t) s += fs[f][t] * wr[t];
        hs[f][o] = fmaxf(s, 0.f);
    }
    __syncthreads();
    for (int idx = tid; idx < 480; idx += 256) {
        int f = idx % 48, t = idx / 48;
        const float* wr = w2 + t * 256;
        float s = 0.f;
        for (int o = 0; o < 256; ++o) s += hs[f][o] * wr[o];
        out[(size_t)b * 480 + t * 48 + f] = s;
    }
}

extern "C" void kernel_launch(void* const* d_in, const int* in_sizes, int n_in,
                              void* d_out, int out_size, void* d_ws, size_t ws_size,
                              hipStream_t stream) {
    (void)in_sizes; (void)n_in; (void)out_size;
    const float* seq     = (const float*)d_in[0];
    // d_in[1..4] = wq1,wq2,wk1,wk2 — dead (attention branch sliced away by combined[:,:,:10])
    const float* gc1_w   = (const float*)d_in[5];
    const float* gc1_att = (const float*)d_in[6];
    const float* gc1_b   = (const float*)d_in[7];
    const float* gcb_w   = (const float*)d_in[8];
    const float* gcb_att = (const float*)d_in[9];
    const float* gcb_b   = (const float*)d_in[10];
    const float* gc7_w   = (const float*)d_in[11];
    const float* gc7_att = (const float*)d_in[12];
    const float* gc7_b   = (const float*)d_in[13];
    const float* mlp_w1  = (const float*)d_in[14];
    const float* mlp_w2  = (const float*)d_in[15];
    const float* ffc_wl  = (const float*)d_in[16];
    const float* ffc_wg  = (const float*)d_in[17];
    float* out = (float*)d_out;
    char* ws = (char*)d_ws;

    // fixed region
    float*    dctm  = (float*)ws;                        // 900 f
    float*    dtail = dctm + 900;                        // 10 f
    char*     p0    = ws + 4096;
    _Float16* Wtb   = (_Float16*)p0;   p0 += 4 * 262144 * 2;   // 4 x (512,512)
    _Float16* Wt1p  = (_Float16*)p0;   p0 += 32768 * 2;        // (512,64) zero-padded
    _Float16* Wt7p  = (_Float16*)p0;   p0 += 8192 * 2;         // (16,512) zero-padded
    _Float16* attp  = (_Float16*)p0;   p0 += 18432 * 2;        // 6 x (48,64) zero-padded
    const size_t fixed_bytes = (size_t)(p0 - ws);

    // per-batch scratch bytes: dct_in 1920 + dct_in_h 6144 + fused 7680
    const size_t per_batch = 15744;
    size_t avail = (ws_size > fixed_bytes) ? (ws_size - fixed_bytes) : 0;
    int nc = 1;
    while ((size_t)(BB / nc) * per_batch > avail && nc < 64) nc *= 2;
    int Bc = BB / nc;

    char* p = ws + fixed_bytes;
    float*    dct_in   = (float*)p;     p += (size_t)Bc * 1920;
    _Float16* dct_in_h = (_Float16*)p;  p += (size_t)Bc * 6144;
    float*    fusedb   = (float*)p;

    prep_kernel<<<492, 256, 0, stream>>>(gcb_w, Wtb, gc1_w, Wt1p, gc7_w, Wt7p,
                                         gc1_att, gcb_att, gc7_att, attp, dctm, dtail);

    for (int ci = 0; ci < nc; ++ci) {
        const float* seqc = seq + (size_t)ci * Bc * TT * FF;
        float* outc = out + (size_t)ci * Bc * 480;
        int n1 = Bc * 3072;
        dct_in_kernel<<<(n1 + 255) / 256, 256, 0, stream>>>(seqc, dctm, dtail, dct_in, dct_in_h, Bc);
        gcn_fused_kernel<<<Bc, 256, 0, stream>>>(dct_in_h, dct_in, Wt1p, Wtb, Wt7p, attp,
                                                 gc1_b, gcb_b, gc7_b, dctm, fusedb);
        ffc_kernel<<<Bc, 256, 0, stream>>>(seqc, ffc_wl, ffc_wg, fusedb);
        mlp_kernel<<<Bc, 256, 0, stream>>>(fusedb, mlp_w1, mlp_w2, outc);
    }
}

// Round 7
// 303.726 us; speedup vs baseline: 1.6040x; 1.6040x over previous
//
#include <hip/hip_runtime.h>
#include <math.h>

#define BB 1024
#define TT 50
#define FF 48
#define EXTN 60
#define NFREQ 31

typedef _Float16 h8 __attribute__((ext_vector_type(8)));
typedef _Float16 h4 __attribute__((ext_vector_type(4)));
typedef float f4 __attribute__((ext_vector_type(4)));

__device__ __forceinline__ float fast_tanh(float x) {
    float e = __expf(2.0f * x);
    return 1.0f - 2.0f * __builtin_amdgcn_rcpf(e + 1.0f);
}

// =============== prep: pack ALL weights into MFMA-fragment order ===============
// Main P layout (per layer): tile t8 = (wv*16+ks)*8+nt ; P[t8*512 + lane*8 + j] =
//   W[k = ks*32+(lane>>4)*8+j][n = wv*128+nt*16+(lane&15)]  -> frag load = base+lane*16.
__global__ void prep_kernel(const float* __restrict__ gcb_w, _Float16* __restrict__ P,
                            const float* __restrict__ gc1_w, _Float16* __restrict__ P1,
                            const float* __restrict__ gc7_w, _Float16* __restrict__ P7,
                            const float* __restrict__ mlp_w1, _Float16* __restrict__ Pw1,
                            const float* __restrict__ mlp_w2, _Float16* __restrict__ Pw2,
                            const float* __restrict__ gc1_att, const float* __restrict__ gcb_att,
                            const float* __restrict__ gc7_att, _Float16* __restrict__ attp,
                            float* __restrict__ dctm, float* __restrict__ dtail) {
    int blk = blockIdx.x, tid = threadIdx.x;
    const _Float16 HZ = (_Float16)0.0f;
    if (blk < 512) {                    // big-layer weights, 4 x 512KB
        int z = blk >> 7;
        int idx = ((blk & 127) << 8) | tid;
        int lane = idx & 63, t8 = idx >> 6;
        int nt = t8 & 7, kw = t8 >> 3;
        int ks = kw & 15, wv = kw >> 4;
        int n = wv * 128 + nt * 16 + (lane & 15);
        int k0 = ks * 32 + (lane >> 4) * 8;
        const float* src = gcb_w + (size_t)z * 262144 + n;
        h8 v;
        #pragma unroll
        for (int j = 0; j < 8; ++j) v[j] = (_Float16)src[(size_t)(k0 + j) * 512];
        *(h8*)(P + (size_t)z * 262144 + (size_t)idx * 8) = v;
    } else if (blk < 528) {             // L1 weights (K=64 padded)
        int idx = ((blk - 512) << 8) | tid;
        int lane = idx & 63, t8 = idx >> 6;
        int nt = t8 & 7, kw = t8 >> 3;
        int ks = kw & 1, wv = kw >> 1;
        int n = wv * 128 + nt * 16 + (lane & 15);
        int k0 = ks * 32 + (lane >> 4) * 8;
        h8 v;
        #pragma unroll
        for (int j = 0; j < 8; ++j) v[j] = (k0 + j < 10) ? (_Float16)gc1_w[(k0 + j) * 512 + n] : HZ;
        *(h8*)(P1 + (size_t)idx * 8) = v;
    } else if (blk < 532) {             // L6 weights (N=16 padded, k split across waves)
        int idx = ((blk - 528) << 8) | tid;
        int lane = idx & 63, t8 = idx >> 6;     // 0..15
        int ks = t8 & 3, wv = t8 >> 2;
        int n = lane & 15;
        int k0 = wv * 128 + ks * 32 + (lane >> 4) * 8;
        h8 v;
        #pragma unroll
        for (int j = 0; j < 8; ++j) v[j] = (n < 10) ? (_Float16)gc7_w[(k0 + j) * 10 + n] : HZ;
        *(h8*)(P7 + (size_t)idx * 8) = v;
    } else if (blk < 540) {             // mlp w1 as B-frags (K=64 padded)
        int idx = ((blk - 532) << 8) | tid;     // 0..2047
        int lane = idx & 63, t8 = idx >> 6;     // 0..31 = ((wv*4+nt)*2+ks)
        int ks = t8 & 1, q = t8 >> 1;
        int nt = q & 3, wv = q >> 2;
        int o = wv * 64 + nt * 16 + (lane & 15);
        int k0 = ks * 32 + (lane >> 4) * 8;
        h8 v;
        #pragma unroll
        for (int j = 0; j < 8; ++j) v[j] = (k0 + j < 40) ? (_Float16)mlp_w1[o * 40 + k0 + j] : HZ;
        *(h8*)(Pw1 + (size_t)idx * 8) = v;
    } else if (blk < 542) {             // mlp w2 as A-frags (M=16 padded rows t)
        int idx = ((blk - 540) << 8) | tid;     // 0..511
        int lane = idx & 63, ks = idx >> 6;     // 0..7
        int m = lane & 15;
        int k0 = ks * 32 + (lane >> 4) * 8;
        h8 v;
        #pragma unroll
        for (int j = 0; j < 8; ++j) v[j] = (m < 10) ? (_Float16)mlp_w2[m * 256 + k0 + j] : HZ;
        *(h8*)(Pw2 + (size_t)idx * 8) = v;
    } else if (blk < 614) {             // att matrices, k zero-padded to 64
        int idx = (blk - 542) * 256 + tid;
        if (idx < 18432) {
            int l = idx / 3072, r = (idx % 3072) / 64, m = idx & 63;
            float v = 0.f;
            if (m < 48) {
                v = (l == 0) ? gc1_att[r * 48 + m]
                  : (l <= 4) ? gcb_att[(l - 1) * 2304 + r * 48 + m]
                             : gc7_att[r * 48 + m];
            }
            attp[idx] = (_Float16)v;
        }
    } else {                            // DCT tables
        int idx = (blk - 614) * 256 + tid;
        if (idx < 900) {
            int d = idx / 30, k = idx % 30;
            double w = (d == 0) ? sqrt(1.0 / 30.0) : sqrt(2.0 / 30.0);
            dctm[idx] = (float)(w * cos(M_PI * (k + 0.5) * d / 30.0));
        } else if (idx < 910) {
            int d = idx - 900;
            double w = (d == 0) ? sqrt(1.0 / 30.0) : sqrt(2.0 / 30.0);
            double s = 0.0;
            for (int k = 10; k < 30; ++k) s += w * cos(M_PI * (k + 0.5) * d / 30.0);
            dtail[d] = (float)s;
        }
    }
}

// =============== one GCN layer on LDS-resident state, packed weights ===============
// State S: 48 rows x 1024 B (512 f16), 16B granules XOR-swizzled by (row&7).
// MODE 0: tanh. MODE 1: tanh + save old state into sv. MODE 2: tanh + add sv.
template<int KSTEPS, int MODE>
__device__ __forceinline__ void gcn_layer(char* S, char* T,
        const _Float16* __restrict__ Pw, const _Float16* __restrict__ attp,
        const float* __restrict__ bias, h4* sv,
        int lane, int wv, int l16, int quad) {
    h8 ab[3][2];
    #pragma unroll
    for (int it = 0; it < 3; ++it)
        #pragma unroll
        for (int ks = 0; ks < 2; ++ks)
            ab[it][ks] = *(const h8*)(attp + (it * 16 + l16) * 64 + ks * 32 + quad * 8);

    f4 acc[3][8];
    #pragma unroll
    for (int mt = 0; mt < 3; ++mt)
        #pragma unroll
        for (int nt = 0; nt < 8; ++nt) acc[mt][nt] = (f4)0.0f;

    const _Float16* Pb = Pw + (size_t)wv * (KSTEPS * 8 * 512) + lane * 8;
    __syncthreads();   // state ready
    const int xm = l16 & 7;
    #pragma unroll 2
    for (int ks = 0; ks < KSTEPS; ++ks) {
        h8 a[3], bfr[8];
        #pragma unroll
        for (int nt = 0; nt < 8; ++nt)
            bfr[nt] = *(const h8*)(Pb + (ks * 8 + nt) * 512);
        #pragma unroll
        for (int mt = 0; mt < 3; ++mt)
            a[mt] = *(h8*)(S + (mt * 16 + l16) * 1024 + (((ks * 4 + quad) ^ xm) << 4));
        #pragma unroll
        for (int mt = 0; mt < 3; ++mt)
            #pragma unroll
            for (int nt = 0; nt < 8; ++nt)
                acc[mt][nt] = __builtin_amdgcn_mfma_f32_16x16x32_f16(a[mt], bfr[nt], acc[mt][nt], 0, 0, 0);
    }
    __syncthreads();   // all reads done; epilogue may overwrite state

    if (lane < 48) {
        int row = lane / 3, s = lane % 3;
        *(h8*)(T + row * 144 + 96 + s * 16) = (h8)(_Float16)0.0f;
    }

    #pragma unroll
    for (int nt = 0; nt < 8; ++nt) {
        #pragma unroll
        for (int mt = 0; mt < 3; ++mt) {
            h4 hv;
            #pragma unroll
            for (int j = 0; j < 4; ++j) hv[j] = (_Float16)acc[mt][nt][j];
            *(h4*)(T + l16 * 144 + (mt * 16 + quad * 4) * 2) = hv;
        }
        asm volatile("s_waitcnt lgkmcnt(0)" ::: "memory");
        h8 tf0 = *(h8*)(T + l16 * 144 + quad * 16);
        h8 tf1 = *(h8*)(T + l16 * 144 + 64 + quad * 16);
        f4 acc2[3];
        #pragma unroll
        for (int it = 0; it < 3; ++it) {
            acc2[it] = __builtin_amdgcn_mfma_f32_16x16x32_f16(tf0, ab[it][0], (f4)0.0f, 0, 0, 0);
            acc2[it] = __builtin_amdgcn_mfma_f32_16x16x32_f16(tf1, ab[it][1], acc2[it], 0, 0, 0);
        }
        const int c0 = wv * 128 + nt * 16 + quad * 4;
        const f4 bv = *(const f4*)(bias + c0);
        #pragma unroll
        for (int it = 0; it < 3; ++it) {
            int f = it * 16 + l16;
            char* sp = S + f * 1024 + (((c0 >> 3) ^ (f & 7)) << 4) + ((c0 & 7) << 1);
            if (MODE == 1) sv[nt * 3 + it] = *(h4*)sp;
            h4 o;
            #pragma unroll
            for (int j = 0; j < 4; ++j) {
                float v = fast_tanh(acc2[it][j] + bv[j]);
                if (MODE == 2) v += (float)sv[nt * 3 + it][j];
                o[j] = (_Float16)v;
            }
            *(h4*)sp = o;
        }
    }
}

// =============== fused GCN: dct_in + L1..L6 + recon, one WG per batch ===============
__launch_bounds__(256, 2)
__global__ void gcn_fused_kernel(const float* __restrict__ seq,
                                 const _Float16* __restrict__ P1,
                                 const _Float16* __restrict__ Pm,
                                 const _Float16* __restrict__ P7,
                                 const _Float16* __restrict__ attp,
                                 const float* __restrict__ gc1_b,
                                 const float* __restrict__ gcb_b,
                                 const float* __restrict__ gc7_b,
                                 const float* __restrict__ dctm,
                                 const float* __restrict__ dtail,
                                 float* __restrict__ fusedb) {
    __shared__ __align__(16) char smem[63744];
    char* S    = smem;              // 48 x 1024 state
    char* R    = smem + 49152;      // 12288: staging / transit / L6 partials / G
    char* dctf = smem + 61440;      // 48 x 12 f32 (dct_in, resid for L6)
    const int tid = threadIdx.x, lane = tid & 63, wv = tid >> 6;
    const int l16 = lane & 15, quad = lane >> 4;
    const int b = blockIdx.x;
    char* T = R + wv * 2304;

    // ---- prologue: seq rows 40..49 + DCT tables -> dct_in -> state ----
    if (tid < 120) *(f4*)(R + tid * 16) = *(const f4*)(seq + (size_t)b * 2400 + 1920 + tid * 4);
    for (int v = tid; v < 310; v += 256)
        ((float*)(R + 2048))[v] = (v < 300) ? dctm[v] : dtail[v - 300];
    __syncthreads();
    for (int v = tid; v < 480; v += 256) {
        int f = v / 10, d = v % 10;
        const float* q = (const float*)R;
        const float* L = (const float*)(R + 2048);
        float a = L[300 + d] * q[9 * 48 + f];
        #pragma unroll
        for (int k = 0; k < 10; ++k) a += L[d * 30 + k] * q[k * 48 + f];
        ((float*)dctf)[f * 12 + d] = a;
    }
    __syncthreads();
    for (int v = tid; v < 384; v += 256) {
        int m = v >> 3, g = v & 7;
        h8 w = (h8)(_Float16)0.0f;
        if (g < 2) {
            #pragma unroll
            for (int j = 0; j < 8; ++j) {
                int d = g * 8 + j;
                if (d < 10) w[j] = (_Float16)((float*)dctf)[m * 12 + d];
            }
        }
        *(h8*)(S + m * 1024 + ((g ^ (m & 7)) << 4)) = w;
    }

    h4 sv[24];
    gcn_layer<2, 0>(S, T, P1,          attp,          gc1_b,        sv, lane, wv, l16, quad);
    gcn_layer<16, 1>(S, T, Pm,          attp + 3072,  gcb_b,        sv, lane, wv, l16, quad);
    gcn_layer<16, 2>(S, T, Pm + 262144, attp + 6144,  gcb_b + 512,  sv, lane, wv, l16, quad);
    gcn_layer<16, 1>(S, T, Pm + 524288, attp + 9216,  gcb_b + 1024, sv, lane, wv, l16, quad);
    gcn_layer<16, 2>(S, T, Pm + 786432, attp + 12288, gcb_b + 1536, sv, lane, wv, l16, quad);

    // ---- L6 (gc7, N=16 padded) + recon ----
    __syncthreads();
    {
        f4 acc[3];
        #pragma unroll
        for (int mt = 0; mt < 3; ++mt) acc[mt] = (f4)0.0f;
        const _Float16* Pb7 = P7 + wv * 2048 + lane * 8;
        #pragma unroll
        for (int ks = 0; ks < 4; ++ks) {
            h8 bfr = *(const h8*)(Pb7 + ks * 512);
            int kh = wv * 128 + ks * 32;
            #pragma unroll
            for (int mt = 0; mt < 3; ++mt) {
                h8 a = *(h8*)(S + (mt * 16 + l16) * 1024 + ((((kh >> 3) + quad) ^ (l16 & 7)) << 4));
                acc[mt] = __builtin_amdgcn_mfma_f32_16x16x32_f16(a, bfr, acc[mt], 0, 0, 0);
            }
        }
        #pragma unroll
        for (int mt = 0; mt < 3; ++mt)
            *(f4*)(R + wv * 3072 + l16 * 192 + (mt * 16 + quad * 4) * 4) = acc[mt];
    }
    __syncthreads();
    if (wv == 0) {
        h4 tw[3]; int ns[3], ms[3];
        #pragma unroll
        for (int q = 0; q < 3; ++q) {
            int idx = lane * 3 + q;
            int n = idx / 12, m0 = (idx % 12) * 4;
            f4 s = *(f4*)(R + n * 192 + m0 * 4);
            s += *(f4*)(R + 3072 + n * 192 + m0 * 4);
            s += *(f4*)(R + 6144 + n * 192 + m0 * 4);
            s += *(f4*)(R + 9216 + n * 192 + m0 * 4);
            h4 h;
            #pragma unroll
            for (int j = 0; j < 4; ++j) h[j] = (_Float16)s[j];
            tw[q] = h; ns[q] = n; ms[q] = m0;
        }
        asm volatile("s_waitcnt lgkmcnt(0)" ::: "memory");
        #pragma unroll
        for (int q = 0; q < 3; ++q) *(h4*)(R + ns[q] * 144 + ms[q] * 2) = tw[q];
        if (lane < 48) {
            int row = lane / 3, s2 = lane % 3;
            *(h8*)(R + row * 144 + 96 + s2 * 16) = (h8)(_Float16)0.0f;
        }
        asm volatile("s_waitcnt lgkmcnt(0)" ::: "memory");
        h8 tf0 = *(h8*)(R + l16 * 144 + quad * 16);
        h8 tf1 = *(h8*)(R + l16 * 144 + 64 + quad * 16);
        const _Float16* a7 = attp + 15360;
        f4 acc2[3];
        #pragma unroll
        for (int it = 0; it < 3; ++it) {
            h8 ab0 = *(const h8*)(a7 + (it * 16 + l16) * 64 + quad * 8);
            h8 ab1 = *(const h8*)(a7 + (it * 16 + l16) * 64 + 32 + quad * 8);
            acc2[it] = __builtin_amdgcn_mfma_f32_16x16x32_f16(tf0, ab0, (f4)0.0f, 0, 0, 0);
            acc2[it] = __builtin_amdgcn_mfma_f32_16x16x32_f16(tf1, ab1, acc2[it], 0, 0, 0);
        }
        char* G = R + 4096;   // 48 x 16 f32
        #pragma unroll
        for (int it = 0; it < 3; ++it) {
            int f = it * 16 + l16;
            #pragma unroll
            for (int j = 0; j < 4; ++j) {
                int c = quad * 4 + j;
                if (c < 10) {
                    float v = acc2[it][j] + gc7_b[c] + ((float*)dctf)[f * 12 + c];
                    *(float*)(G + f * 64 + c * 4) = v;
                }
            }
        }
    }
    __syncthreads();
    {
        char* G = R + 4096;
        for (int v = tid; v < 1440; v += 256) {
            int f = v / 30, t = v % 30;
            float s = 0.f;
            #pragma unroll
            for (int d = 0; d < 10; ++d) s += dctm[d * 30 + t] * *(float*)(G + f * 64 + d * 4);
            fusedb[(size_t)b * 1440 + v] = s;
        }
    }
}

// =============== fused FFC (direct DFT) + MLP head (MFMA) ===============
__launch_bounds__(256, 3)
__global__ void ffc_mlp_kernel(const float* __restrict__ seq,
                               const float* __restrict__ fusedb,
                               const float* __restrict__ wl,
                               const float* __restrict__ wg,
                               const _Float16* __restrict__ Pw1,
                               const _Float16* __restrict__ Pw2,
                               float* __restrict__ out) {
    __shared__ __align__(16) char smem[45312];
    float* ext = (float*)smem;                 // [60][48], dead after fus fill
    float* Xre = (float*)(smem + 11520);       // [48][32]
    float* Xim = (float*)(smem + 17664);       // [48][32]
    float* Yo  = (float*)(smem + 23808);       // [6][16][32]
    _Float16* hlds = (_Float16*)smem;          // [48][264]  (overlays ext/Xre/Xim)
    char* R2 = smem + 25344;                   // 12288 partials (overlays Yo tail)
    _Float16* fus = (_Float16*)(smem + 37632); // [48][72]  (pitch 144 B)
    float* c60 = (float*)(smem + 44544);
    float* s60 = (float*)(smem + 44784);
    float* wls = (float*)(smem + 45024);
    float* wgs = (float*)(smem + 45072);

    const int b = blockIdx.x, tid = threadIdx.x;
    const int lane = tid & 63, wv = tid >> 6;
    const int l16 = lane & 15, quad = lane >> 4;
    const float* s = seq + (size_t)b * TT * FF;

    for (int idx = tid; idx < EXTN * FF; idx += 256) {
        int t = idx / FF, f = idx % FF;
        int ts = t < TT ? t : TT - 1;
        ext[t * FF + f] = s[ts * FF + f];
    }
    if (tid < 60) { c60[tid] = cospif(tid / 30.0f); s60[tid] = sinpif(tid / 30.0f); }
    if (tid >= 64 && tid < 73) wls[tid - 64] = wl[tid - 64];
    if (tid >= 128 && tid < 164) wgs[tid - 128] = wg[tid - 128];
    __syncthreads();
    for (int idx = tid; idx < FF * NFREQ; idx += 256) {
        int f = idx % FF, k = idx / FF;
        float re = 0.f, im = 0.f;
        int kt = 0;
        for (int t = 0; t < EXTN; ++t) {
            float v = ext[t * FF + f];
            re += v * c60[kt];
            im -= v * s60[kt];
            kt += k; kt = (kt >= 60) ? kt - 60 : kt;
        }
        Xre[f * 32 + k] = re; Xim[f * 32 + k] = im;
    }
    __syncthreads();
    for (int idx = tid; idx < 6 * 16 * NFREQ; idx += 256) {
        int k = idx % NFREQ; int g = (idx / NFREQ) % 16; int o = idx / (NFREQ * 16);
        float v = wgs[o * 6 + 0] * Xre[g * 32 + k]        + wgs[o * 6 + 1] * Xre[(16 + g) * 32 + k]
                + wgs[o * 6 + 2] * Xre[(32 + g) * 32 + k] + wgs[o * 6 + 3] * Xim[g * 32 + k]
                + wgs[o * 6 + 4] * Xim[(16 + g) * 32 + k] + wgs[o * 6 + 5] * Xim[(32 + g) * 32 + k];
        Yo[(o * 16 + g) * 32 + k] = fmaxf(v, 0.f);
    }
    __syncthreads();
    // ---- build fus (48 x 64 f16, pitch 72 halves): recon (global) + ffc + zero pad ----
    for (int v = tid; v < 1440; v += 256) {
        int f = v / 30, t = v % 30;
        fus[f * 72 + t] = (_Float16)fusedb[(size_t)b * 1440 + v];
    }
    for (int v = tid; v < 1152; v += 256) {
        int f = v / 24, t = 40 + v % 24;
        fus[f * 72 + t] = (_Float16)0.0f;
    }
    for (int idx = tid; idx < 480; idx += 256) {
        int t = idx % 10; int g = (idx / 10) % 16; int c = idx / 160;
        float acc = Yo[(c * 16 + g) * 32 + 0] + Yo[(c * 16 + g) * 32 + 30] * ((t & 1) ? -1.f : 1.f);
        float s2 = 0.f;
        int kt = t;
        for (int k = 1; k < 30; ++k) {
            s2 += Yo[(c * 16 + g) * 32 + k] * c60[kt] - Yo[((c + 3) * 16 + g) * 32 + k] * s60[kt];
            kt += t; kt = (kt >= 60) ? kt - 60 : kt;
        }
        acc = (acc + 2.f * s2) * (1.0f / 60.0f);
        float loc = wls[c * 3 + 0] * ext[t * FF + g] + wls[c * 3 + 1] * ext[t * FF + 16 + g]
                  + wls[c * 3 + 2] * ext[t * FF + 32 + g];
        int f = c * 16 + g;
        fus[f * 72 + 30 + t] = (_Float16)(acc + loc);
    }
    __syncthreads();
    // ---- mlp1: h = relu(fus @ w1^T) via MFMA; per wave o-slice 64 ----
    f4 acc1[3][4];
    #pragma unroll
    for (int mt = 0; mt < 3; ++mt)
        #pragma unroll
        for (int nt = 0; nt < 4; ++nt) acc1[mt][nt] = (f4)0.0f;
    #pragma unroll
    for (int ks = 0; ks < 2; ++ks) {
        h8 af[3], bf[4];
        #pragma unroll
        for (int mt = 0; mt < 3; ++mt)
            af[mt] = *(h8*)((char*)fus + (mt * 16 + l16) * 144 + ks * 64 + quad * 16);
        #pragma unroll
        for (int nt = 0; nt < 4; ++nt)
            bf[nt] = *(const h8*)(Pw1 + (size_t)(((wv * 4 + nt) * 2 + ks) * 512) + lane * 8);
        #pragma unroll
        for (int mt = 0; mt < 3; ++mt)
            #pragma unroll
            for (int nt = 0; nt < 4; ++nt)
                acc1[mt][nt] = __builtin_amdgcn_mfma_f32_16x16x32_f16(af[mt], bf[nt], acc1[mt][nt], 0, 0, 0);
    }
    __syncthreads();   // ext/Xre/Xim/Yo dead -> hlds region free
    #pragma unroll
    for (int mt = 0; mt < 3; ++mt)
        #pragma unroll
        for (int nt = 0; nt < 4; ++nt) {
            int o = wv * 64 + nt * 16 + l16;
            #pragma unroll
            for (int j = 0; j < 4; ++j) {
                int f = mt * 16 + quad * 4 + j;
                hlds[f * 264 + o] = (_Float16)fmaxf(acc1[mt][nt][j], 0.f);
            }
        }
    __syncthreads();
    // ---- mlp2: out^T[t][f] = w2 @ h^T via MFMA, k split across waves ----
    f4 acc2[3];
    #pragma unroll
    for (int nt3 = 0; nt3 < 3; ++nt3) acc2[nt3] = (f4)0.0f;
    #pragma unroll
    for (int ss = 0; ss < 2; ++ss) {
        int ks = wv * 2 + ss;
        h8 aw = *(const h8*)(Pw2 + (size_t)ks * 512 + lane * 8);
        #pragma unroll
        for (int nt3 = 0; nt3 < 3; ++nt3) {
            h8 bh = *(h8*)((char*)hlds + (nt3 * 16 + l16) * 528 + ks * 64 + quad * 16);
            acc2[nt3] = __builtin_amdgcn_mfma_f32_16x16x32_f16(aw, bh, acc2[nt3], 0, 0, 0);
        }
    }
    #pragma unroll
    for (int nt3 = 0; nt3 < 3; ++nt3)
        *(f4*)(R2 + wv * 3072 + (nt3 * 16 + l16) * 64 + quad * 16) = acc2[nt3];
    __syncthreads();
    for (int v = tid; v < 768; v += 256) {
        int f = v >> 4, t = v & 15;
        float sm = 0.f;
        #pragma unroll
        for (int w4 = 0; w4 < 4; ++w4) sm += *(float*)(R2 + w4 * 3072 + f * 64 + t * 4);
        if (t < 10) out[(size_t)b * 480 + t * 48 + f] = sm;
    }
}

extern "C" void kernel_launch(void* const* d_in, const int* in_sizes, int n_in,
                              void* d_out, int out_size, void* d_ws, size_t ws_size,
                              hipStream_t stream) {
    (void)in_sizes; (void)n_in; (void)out_size;
    const float* seq     = (const float*)d_in[0];
    // d_in[1..4] = wq1,wq2,wk1,wk2 — dead (attention branch sliced away by combined[:,:,:10])
    const float* gc1_w   = (const float*)d_in[5];
    const float* gc1_att = (const float*)d_in[6];
    const float* gc1_b   = (const float*)d_in[7];
    const float* gcb_w   = (const float*)d_in[8];
    const float* gcb_att = (const float*)d_in[9];
    const float* gcb_b   = (const float*)d_in[10];
    const float* gc7_w   = (const float*)d_in[11];
    const float* gc7_att = (const float*)d_in[12];
    const float* gc7_b   = (const float*)d_in[13];
    const float* mlp_w1  = (const float*)d_in[14];
    const float* mlp_w2  = (const float*)d_in[15];
    const float* ffc_wl  = (const float*)d_in[16];
    const float* ffc_wg  = (const float*)d_in[17];
    float* out = (float*)d_out;
    char* ws = (char*)d_ws;

    // fixed region (16B-aligned slabs)
    float*    dctm  = (float*)ws;                      // 900 f
    float*    dtail = dctm + 900;                      // 10 f
    char*     p0    = ws + 4096;
    _Float16* Pm   = (_Float16*)p0;   p0 += 4 * 262144 * 2;   // packed big-layer weights
    _Float16* P1   = (_Float16*)p0;   p0 += 32768 * 2;
    _Float16* P7   = (_Float16*)p0;   p0 += 8192 * 2;
    _Float16* Pw1  = (_Float16*)p0;   p0 += 16384 * 2;
    _Float16* Pw2  = (_Float16*)p0;   p0 += 4096 * 2;
    _Float16* attp = (_Float16*)p0;   p0 += 18432 * 2;
    const size_t fixed_bytes = (size_t)(p0 - ws);

    const size_t per_batch = 5760;   // fusedb: 48 x 30 f32
    size_t avail = (ws_size > fixed_bytes) ? (ws_size - fixed_bytes) : 0;
    int nc = 1;
    while ((size_t)(BB / nc) * per_batch > avail && nc < 64) nc *= 2;
    int Bc = BB / nc;
    float* fusedb = (float*)(ws + fixed_bytes);

    prep_kernel<<<618, 256, 0, stream>>>(gcb_w, Pm, gc1_w, P1, gc7_w, P7,
                                         mlp_w1, Pw1, mlp_w2, Pw2,
                                         gc1_att, gcb_att, gc7_att, attp, dctm, dtail);

    for (int ci = 0; ci < nc; ++ci) {
        const float* seqc = seq + (size_t)ci * Bc * TT * FF;
        float* outc = out + (size_t)ci * Bc * 480;
        gcn_fused_kernel<<<Bc, 256, 0, stream>>>(seqc, P1, Pm, P7, attp,
                                                 gc1_b, gcb_b, gc7_b, dctm, dtail, fusedb);
        ffc_mlp_kernel<<<Bc, 256, 0, stream>>>(seqc, fusedb, ffc_wl, ffc_wg, Pw1, Pw2, outc);
    }
}